// Round 9
// baseline (150.015 us; speedup 1.0000x reference)
//
#include <hip/hip_runtime.h>
#include <math.h>

// Problem constants (reference: N=64, H=512, W=512, RATIO=2, ITERATIONS=1)
#define NIMG 64
#define HH 512
#define WW 512
#define NPIX (NIMG * HH * WW)          // 16,777,216
#define NBLK 8192                      // 2^21 threads, 8 px each
#define MASK_BYTES (NPIX / 8)          // 2 MB: 1 bit per pixel
#define INV_TOTAL (1.0f / 16777216.0f) // exact pow2

typedef unsigned int u32;
typedef unsigned char u8;

// ---------------- Kernel A: y (int32, 64 MB) -> bitmask (2 MB) -------------
// Byte i of mask = pixels 8i..8i+7, bit k = (y[8i+k] > 0). Thread idx owns
// byte idx. Pure stream: 2 int4 loads, 1 byte store.
__global__ __launch_bounds__(256, 8) void border_mask_gen(
    const int* __restrict__ y, u8* __restrict__ mask)
{
    const int idx = blockIdx.x * 256 + threadIdx.x;
    const int4 a = ((const int4*)y)[idx * 2];
    const int4 b = ((const int4*)y)[idx * 2 + 1];
    u32 m = (a.x > 0)       | ((a.y > 0) << 1)
          | ((a.z > 0) << 2) | ((a.w > 0) << 3)
          | ((b.x > 0) << 4) | ((b.y > 0) << 5)
          | ((b.z > 0) << 6) | ((b.w > 0) << 7);
    mask[idx] = (u8)m;
}

// ---------------- Kernel B: x (fp32, 64 MB) + bitmask -> weighted loss -----
// One wave == one image row (64 lanes x 8 px). Morphology on 8-bit lane
// masks: vertical OR/AND from 3 mask-row bytes (replicate row clamp — exact
// for idempotent OR/AND), horizontal via shifts + 2 shfls (wave edge ==
// image edge, replicate). border = ho ^ ha (OR superset of AND).
__global__ __launch_bounds__(256, 8) void border_loss_bits(
    const float* __restrict__ x, const u8* __restrict__ mask,
    float* __restrict__ part, int atomic_mode)
{
    __shared__ float wsum[4];

    const int tid  = threadIdx.x;
    const int idx  = blockIdx.x * 256 + tid;
    const int lane = tid & 63;               // == idx & 63 (256-aligned)
    const int r    = (idx >> 6) & (HH - 1);  // image row (one per wave)
    const int n    = idx >> 15;              // image
    const int mrC  = (n << 9) | r;           // mask row index
    const int mrT  = (r > 0)      ? mrC - 1 : mrC;   // replicate clamp
    const int mrB  = (r < HH - 1) ? mrC + 1 : mrC;

    // ---- loads: 3 mask bytes + 2 float4 of x (all independent)
    const u32 mt = mask[(mrT << 6) + lane];
    const u32 mc = mask[(mrC << 6) + lane];
    const u32 mb = mask[(mrB << 6) + lane];
    const float4 xa = *(const float4*)(x + (idx << 3));
    const float4 xb = *(const float4*)(x + (idx << 3) + 4);

    // ---- vertical OR / AND (8 cols at once)
    const u32 vo = mt | mc | mb;
    const u32 va = mt & mc & mb;

    // ---- neighbor edge bits across lanes (image edge: replicate self)
    const int iL = (lane + 63) & 63, iR = (lane + 1) & 63;
    const u32 voL = __shfl(vo, iL), vaL = __shfl(va, iL);
    const u32 voR = __shfl(vo, iR), vaR = __shfl(va, iR);
    const u32 lbO = (lane == 0)  ? (vo & 1u)        : ((voL >> 7) & 1u);
    const u32 lbA = (lane == 0)  ? (va & 1u)        : ((vaL >> 7) & 1u);
    const u32 rbO = (lane == 63) ? ((vo >> 7) & 1u) : (voR & 1u);
    const u32 rbA = (lane == 63) ? ((va >> 7) & 1u) : (vaR & 1u);

    // ---- horizontal 3-window OR / AND; border bits = ho ^ ha (bits 0..7)
    const u32 ho = vo | ((vo << 1) | lbO) | ((vo >> 1) | (rbO << 7));
    const u32 ha = va & ((va << 1) | lbA) & ((va >> 1) | (rbA << 7));
    const u32 bd = ho ^ ha;

    // ---- per-pixel: max(x,0) - x*m + ln(1+e^{-|x|}) == max(m?-x:x,0)+softplus
    float acc = 0.0f;
#define PX(xf, k) { \
        const float ls = fmaxf(((mc >> (k)) & 1u) ? -(xf) : (xf), 0.0f) \
                       + __logf(1.0f + __expf(-fabsf(xf))); \
        acc = fmaf(ls, ((bd >> (k)) & 1u) ? 2.0f : 1.0f, acc); }
    PX(xa.x, 0) PX(xa.y, 1) PX(xa.z, 2) PX(xa.w, 3)
    PX(xb.x, 4) PX(xb.y, 5) PX(xb.z, 6) PX(xb.w, 7)
#undef PX

    // ---- reduction: wave shuffle + tiny LDS across 4 waves
    #pragma unroll
    for (int off = 32; off > 0; off >>= 1)
        acc += __shfl_down(acc, off);
    if ((tid & 63) == 0) wsum[tid >> 6] = acc;
    __syncthreads();
    if (tid == 0) {
        const float t = wsum[0] + wsum[1] + wsum[2] + wsum[3];
        if (atomic_mode) atomicAdd(part, t * INV_TOTAL);
        else             part[blockIdx.x] = t;
    }
}

// ---------------- Fallback (R8): fused, y read 3x — used if ws too small ---
__global__ __launch_bounds__(256, 8) void border_loss_fused(
    const float* __restrict__ x, const int* __restrict__ y,
    float* __restrict__ part, int atomic_mode)
{
    __shared__ float wsum[4];
    const int tid  = threadIdx.x;
    const int idx  = blockIdx.x * 256 + tid;
    const int lane = tid & 63;
    const int r    = (idx >> 6) & (HH - 1);
    const int n    = idx >> 15;
    const int rowb = n * (HH * WW) + r * WW;
    const int col  = lane << 3;
    const int pC = rowb + col;
    const int pT = pC + ((r > 0)      ? -WW : 0);
    const int pB = pC + ((r < HH - 1) ?  WW : 0);

    const int4   t0 = *(const int4*)(y + pT);
    const int4   t1 = *(const int4*)(y + pT + 4);
    const int4   c0 = *(const int4*)(y + pC);
    const int4   c1 = *(const int4*)(y + pC + 4);
    const int4   b0 = *(const int4*)(y + pB);
    const int4   b1 = *(const int4*)(y + pB + 4);
    const float4 xa = *(const float4*)(x + pC);
    const float4 xb = *(const float4*)(x + pC + 4);

    const int vo0 = t0.x | c0.x | b0.x;  const int va0 = t0.x & c0.x & b0.x;
    const int vo1 = t0.y | c0.y | b0.y;  const int va1 = t0.y & c0.y & b0.y;
    const int vo2 = t0.z | c0.z | b0.z;  const int va2 = t0.z & c0.z & b0.z;
    const int vo3 = t0.w | c0.w | b0.w;  const int va3 = t0.w & c0.w & b0.w;
    const int vo4 = t1.x | c1.x | b1.x;  const int va4 = t1.x & c1.x & b1.x;
    const int vo5 = t1.y | c1.y | b1.y;  const int va5 = t1.y & c1.y & b1.y;
    const int vo6 = t1.z | c1.z | b1.z;  const int va6 = t1.z & c1.z & b1.z;
    const int vo7 = t1.w | c1.w | b1.w;  const int va7 = t1.w & c1.w & b1.w;

    const int iL = (lane + 63) & 63, iR = (lane + 1) & 63;
    const int voLs = __shfl(vo7, iL), vaLs = __shfl(va7, iL);
    const int voRs = __shfl(vo0, iR), vaRs = __shfl(va0, iR);
    const int voL = (lane == 0)  ? vo0 : voLs;
    const int vaL = (lane == 0)  ? va0 : vaLs;
    const int voR = (lane == 63) ? vo7 : voRs;
    const int vaR = (lane == 63) ? va7 : vaRs;

    const int ho0 = voL | vo0 | vo1;  const int ha0 = vaL & va0 & va1;
    const int ho1 = vo0 | vo1 | vo2;  const int ha1 = va0 & va1 & va2;
    const int ho2 = vo1 | vo2 | vo3;  const int ha2 = va1 & va2 & va3;
    const int ho3 = vo2 | vo3 | vo4;  const int ha3 = va2 & va3 & va4;
    const int ho4 = vo3 | vo4 | vo5;  const int ha4 = va3 & va4 & va5;
    const int ho5 = vo4 | vo5 | vo6;  const int ha5 = va4 & va5 & va6;
    const int ho6 = vo5 | vo6 | vo7;  const int ha6 = va5 & va6 & va7;
    const int ho7 = vo6 | vo7 | voR;  const int ha7 = va6 & va7 & vaR;

    float acc = 0.0f;
#define PX(xf, m, ho, ha) { \
        const float ls = fmaxf((m) ? -(xf) : (xf), 0.0f) \
                       + __logf(1.0f + __expf(-fabsf(xf))); \
        acc = fmaf(ls, (float)(1 + ((ho) ^ (ha))), acc); }
    PX(xa.x, c0.x, ho0, ha0) PX(xa.y, c0.y, ho1, ha1)
    PX(xa.z, c0.z, ho2, ha2) PX(xa.w, c0.w, ho3, ha3)
    PX(xb.x, c1.x, ho4, ha4) PX(xb.y, c1.y, ho5, ha5)
    PX(xb.z, c1.z, ho6, ha6) PX(xb.w, c1.w, ho7, ha7)
#undef PX

    #pragma unroll
    for (int off = 32; off > 0; off >>= 1)
        acc += __shfl_down(acc, off);
    if ((tid & 63) == 0) wsum[tid >> 6] = acc;
    __syncthreads();
    if (tid == 0) {
        const float t = wsum[0] + wsum[1] + wsum[2] + wsum[3];
        if (atomic_mode) atomicAdd(part, t * INV_TOTAL);
        else             part[blockIdx.x] = t;
    }
}

__global__ __launch_bounds__(256) void border_loss_reduce(
    const float* __restrict__ part, float* __restrict__ out)
{
    __shared__ float wsum[4];
    float t = 0.0f;
    for (int i = threadIdx.x; i < NBLK; i += 256) t += part[i];
    #pragma unroll
    for (int off = 32; off > 0; off >>= 1)
        t += __shfl_down(t, off);
    if ((threadIdx.x & 63) == 0) wsum[threadIdx.x >> 6] = t;
    __syncthreads();
    if (threadIdx.x == 0)
        out[0] = (wsum[0] + wsum[1] + wsum[2] + wsum[3]) * INV_TOTAL;
}

__global__ void border_loss_zero(float* out) { out[0] = 0.0f; }

extern "C" void kernel_launch(void* const* d_in, const int* in_sizes, int n_in,
                              void* d_out, int out_size, void* d_ws, size_t ws_size,
                              hipStream_t stream)
{
    const float* x = (const float*)d_in[0];
    const int*   y = (const int*)d_in[1];
    float* out = (float*)d_out;

    if (ws_size >= (size_t)MASK_BYTES + (size_t)NBLK * sizeof(float)) {
        // Two-pass: y->bitmask (1x y read), then x + bitmask -> loss.
        u8*    mask = (u8*)d_ws;
        float* part = (float*)((char*)d_ws + MASK_BYTES);
        border_mask_gen<<<NBLK, 256, 0, stream>>>(y, mask);
        border_loss_bits<<<NBLK, 256, 0, stream>>>(x, mask, part, 0);
        border_loss_reduce<<<1, 256, 0, stream>>>(part, out);
    } else if (ws_size >= (size_t)NBLK * sizeof(float)) {
        float* part = (float*)d_ws;
        border_loss_fused<<<NBLK, 256, 0, stream>>>(x, y, part, 0);
        border_loss_reduce<<<1, 256, 0, stream>>>(part, out);
    } else {
        border_loss_zero<<<1, 1, 0, stream>>>(out);
        border_loss_fused<<<NBLK, 256, 0, stream>>>(x, y, out, 1);
    }
}